// Round 3
// baseline (408.582 us; speedup 1.0000x reference)
//
#include <hip/hip_runtime.h>
#include <stdint.h>

// Problem constants
#define B_SZ   32
#define NIN    2312
#define NHID   512
#define NOUT   10
#define T_SZ   350
#define NW32   73                 // ceil(2312/32) bitmask words per input column
#define NW64   8                  // 512/64 ballot words per hidden column
#define NHALF  256                // output half-width for L2-resident W1
#define NROW   2313               // NIN + 1 dummy zero row (branch-free padding)

// psp (SRM) kernel eps[n] = CS * n * DS^n, DS = exp(-0.1), CS = e/10
#define DS_D   0.9048374180359595
#define CS_D   0.2718281828459045
#define D100_D 4.5399929762484854e-05   // exp(-10) = DS^100
// refractory recurrence in fp32, exactly like the reference scan
#define DREF_F 0.36787944117144233f     // exp(-1)
#define CREF_F -54.36563656918091f      // -2*10*e

// scan chunking (k45/k6): 7 chunks of 50; psp-IIR warm-started <=100 steps
// early is EXACT (FIR truncated at 100 taps); refractory burn-in error decays
// e^-n -> < 1e-28 by chunk start (absorbed below fp32 ulp).
#define NCHUNK 7
#define CLEN   50
#define NPF    10                 // ring depth; 50/100/150 all %10==0

// ---------------------------------------------------------------------------
// K12: fused bitpack (blocks 0..2335) + W1 half-split pack (2336..3503) +
//      dummy-zero-row fill (block 3504). Bitpack float4 streaming.
__global__ __launch_bounds__(384) void k12(const float* __restrict__ x,
                                           const float* __restrict__ W1,
                                           uint32_t* __restrict__ bits1,
                                           float* __restrict__ W1s) {
    __shared__ float lds[32 * T_SZ];   // 44.8 KB
    const int bid = blockIdx.x;
    const int tid = threadIdx.x;
    if (bid < NW32 * B_SZ) {
        // --- bitpack: block = (b, w); contiguous rowsx350 tile -> LDS -> pack
        const int w = bid % NW32;
        const int b = bid / NW32;
        const int rows = (NIN - (w << 5) < 32) ? (NIN - (w << 5)) : 32;  // 32 or 8
        const float* base = x + ((size_t)(b * NIN + (w << 5))) * T_SZ;
        const int nf4 = (rows * T_SZ) >> 2;     // rows even -> divisible by 4
        for (int f = tid; f < nf4; f += 384)
            ((float4*)lds)[f] = ((const float4*)base)[f];
        __syncthreads();
        if (tid < T_SZ) {
            uint32_t bits = 0;
            for (int j = 0; j < rows; ++j)
                bits |= (lds[j * T_SZ + tid] > 0.5f) ? (1u << j) : 0u;
            bits1[(size_t)(b * T_SZ + tid) * NW32 + w] = bits;
        }
    } else if (bid < NW32 * B_SZ + NW32 * 16) {
        // --- pack W1 [512, 2312] -> W1s[h][i][256], h = o>>8
        float (*tile)[33] = (float (*)[33])lds;
        const int bb = bid - NW32 * B_SZ;
        const int i0 = (bb % NW32) * 32, o0 = (bb / NW32) * 32;
        const int tx = tid & 31, ty = tid >> 5;  // ty 0..11
#pragma unroll
        for (int r = 0; r < 3; ++r) {
            int row = ty + 12 * r;
            if (row < 32) {
                int o = o0 + row, i = i0 + tx;
                if (i < NIN) tile[row][tx] = W1[(size_t)o * NIN + i];
            }
        }
        __syncthreads();
#pragma unroll
        for (int r = 0; r < 3; ++r) {
            int row = ty + 12 * r;
            if (row < 32) {
                int i = i0 + row, o = o0 + tx;
                if (i < NIN)
                    W1s[((size_t)(o >> 8) * NROW + i) * NHALF + (o & 255)] = tile[tx][row];
            }
        }
    } else {
        // --- dummy zero row i = NIN for both halves
        if (tid < NHALF) {
            W1s[((size_t)0 * NROW + NIN) * NHALF + tid] = 0.0f;
            W1s[((size_t)1 * NROW + NIN) * NHALF + tid] = 0.0f;
        }
    }
}

// ---------------------------------------------------------------------------
// K3: sparse dense1 (R6/R10 gather form — the measured optimum: 101us,
// 26.3 TB/s L2-gather = 76% of streaming ubench). Half-split for L2
// residency; single-wave shfl prefix scan; branch-free 4-deep pipelined row
// loop via dummy zero-row padding. Batching/LDS-staging variants all lose
// (R7/R8/R9/R11/R12 post-mortems): VALU/divergence tax > traffic savings.
//
// R13 post-mortem: XCD swizzle cut FETCH 23->13.8 MB but time flat ->
// k3 is L2-HIT-SERVICE-RATE bound at 26.4 TB/s (76% of streaming ubench;
// random 1KB-row gather). Structural ceiling given the bit-exact sum order.
// R14 post-mortem: 4-way split cost +14us (tails+gaps), no profiling gain
// (harness fill kernels flood top-5). Restored to single dispatch (R13 form).
__global__ __launch_bounds__(256) void k3_dense1(const uint32_t* __restrict__ bits1,
                                                 const float* __restrict__ W1s,
                                                 float* __restrict__ z1ct) {
    __shared__ uint32_t words[128];
    __shared__ uint16_t pfx[80];
    __shared__ uint16_t idxbuf[NIN + 16];
    __shared__ float red[3][NHALF];
    __shared__ float fin[NHALF];

    const int id = blockIdx.x;
    const int h = (id >> 2) & 1;                  // XCD-affine half select
    const int bt = ((id >> 3) << 2) | (id & 3);   // b*350 + t (bijective)
    const int tid = threadIdx.x;
    const int wv = tid >> 6, lane = tid & 63;

    if (tid < 128) words[tid] = (tid < NW32) ? bits1[(size_t)bt * NW32 + tid] : 0u;
    __syncthreads();

    if (wv == 0) {
        uint32_t w0 = words[lane];
        uint32_t w1 = words[lane + 64];
        int p0 = __popc(w0), p1 = __popc(w1);
        int s0 = p0, s1 = p1;
#pragma unroll
        for (int off = 1; off < 64; off <<= 1) {
            int u0 = __shfl_up(s0, off);
            int u1 = __shfl_up(s1, off);
            if (lane >= off) { s0 += u0; s1 += u1; }
        }
        int tot0 = __shfl(s0, 63);
        pfx[lane] = (uint16_t)(s0 - p0);
        if (lane < 9) pfx[lane + 64] = (uint16_t)(tot0 + s1 - p1);
        if (lane == 8) pfx[73] = (uint16_t)(tot0 + s1);   // ntot
    }
    __syncthreads();

    const int ntot = pfx[73];
    const int npad = (ntot + 15) & ~15;
    if (tid < NW32) {
        uint32_t m = words[tid];
        int p = pfx[tid];
        while (m) {
            int j = __builtin_ctz(m);
            m &= m - 1;
            idxbuf[p++] = (uint16_t)((tid << 5) + j);
        }
    }
    if (tid >= 240) {                   // pad to multiple of 16 with zero row
        int k = tid - 240;
        if (ntot + k < npad) idxbuf[ntot + k] = (uint16_t)NIN;
    }
    __syncthreads();

    const float* Wh = W1s + (size_t)h * NROW * NHALF;
    float4 acc = make_float4(0.f, 0.f, 0.f, 0.f);
    for (int r = wv; r < npad; r += 16) {
        int i0 = idxbuf[r], i1 = idxbuf[r + 4], i2 = idxbuf[r + 8], i3 = idxbuf[r + 12];
        float4 v0 = ((const float4*)(Wh + (size_t)i0 * NHALF))[lane];
        float4 v1 = ((const float4*)(Wh + (size_t)i1 * NHALF))[lane];
        float4 v2 = ((const float4*)(Wh + (size_t)i2 * NHALF))[lane];
        float4 v3 = ((const float4*)(Wh + (size_t)i3 * NHALF))[lane];
        acc.x += v0.x; acc.y += v0.y; acc.z += v0.z; acc.w += v0.w;
        acc.x += v1.x; acc.y += v1.y; acc.z += v1.z; acc.w += v1.w;
        acc.x += v2.x; acc.y += v2.y; acc.z += v2.z; acc.w += v2.w;
        acc.x += v3.x; acc.y += v3.y; acc.z += v3.z; acc.w += v3.w;
    }
    if (wv > 0) ((float4*)red[wv - 1])[lane] = acc;
    __syncthreads();
    if (wv == 0) {
        float4 a1 = ((float4*)red[0])[lane];
        float4 a2 = ((float4*)red[1])[lane];
        float4 a3 = ((float4*)red[2])[lane];
        acc.x = ((acc.x + a1.x) + a2.x) + a3.x;
        acc.y = ((acc.y + a1.y) + a2.y) + a3.y;
        acc.z = ((acc.z + a1.z) + a2.z) + a3.z;
        acc.w = ((acc.w + a1.w) + a2.w) + a3.w;
        ((float4*)fin)[lane] = acc;
    }
    __syncthreads();
    const int och = (h << 8) + tid;
    const int oc = och >> 6, l6 = och & 63;
    const int b = bt / T_SZ, t = bt - b * T_SZ;
    z1ct[((size_t)(b * NW64 + oc) * T_SZ + t) * 64 + l6] = fin[tid];
}

// ---------------------------------------------------------------------------
// K45: fused layer-1 scan + dense2. Block = (b, chunk), 512 threads = 8 waves;
// wave wv scans channels wv*64..+63 (chunked IIR, exact), ballots into LDS;
// then 500 (t,o) pairs compute z2 in the same wv/ctz-ascending order.
__global__ __launch_bounds__(512) void k45(const float* __restrict__ z1ct,
                                           const float* __restrict__ W2,
                                           float* __restrict__ z2ct) {
    __shared__ float W2s[NHID * NOUT];      // [c][o], 20 KB
    __shared__ uint64_t sw[CLEN][NW64];     // s1 ballot words for my 50 t's
    const int tid = threadIdx.x;
    const int wv = tid >> 6, lane = tid & 63;
    const int b = blockIdx.x / NCHUNK;
    const int ck = blockIdx.x % NCHUNK;
    const int tstart = ck * CLEN;
    const int tend = tstart + CLEN;
    const int t0 = (tstart >= 100) ? tstart - 100 : 0;

    for (int k = tid; k < NHID * NOUT; k += 512) {
        int c = k / NOUT, o = k - c * NOUT;
        W2s[k] = W2[(size_t)o * NHID + c];
    }

    // ---- layer-1 chunked scan (identical math to old k4)
    const float* base = z1ct + (size_t)(b * NW64 + wv) * T_SZ * 64 + lane;
    double A = 0.0, Bs = 0.0, A2 = 0.0, Bs2 = 0.0;
    float ra = 0.0f, rb = 0.0f;
    const double TAIL = D100_D * CS_D;
    float xb[NPF], xdb[NPF];
#pragma unroll
    for (int i = 0; i < NPF; ++i) {
        int t = t0 + i;
        xb[i] = base[(size_t)t * 64];
        int td = t - 100;
        xdb[i] = (td >= 0) ? base[(size_t)td * 64] : 0.0f;
    }
    for (int tb = t0; tb < tend; tb += NPF) {
#pragma unroll
        for (int i = 0; i < NPF; ++i) {
            const int t = tb + i;
            float x = xb[i], xd = xdb[i];
            const int tn = t + NPF;
            xb[i] = (tn < T_SZ) ? base[(size_t)tn * 64] : 0.0f;
            const int td = tn - 100;
            xdb[i] = (td >= 0) ? base[(size_t)td * 64] : 0.0f;
            Bs = DS_D * Bs + DS_D * A;
            A = DS_D * A + (double)x;
            Bs2 = DS_D * Bs2 + DS_D * A2;
            A2 = DS_D * A2 + (double)xd;
            double y = CS_D * Bs - TAIL * (Bs2 + 100.0 * A2);
            float u = (float)y + CREF_F * rb;
            float s = (u >= 10.0f) ? 1.0f : 0.0f;
            float ran = DREF_F * ra + s;
            float rbn = DREF_F * rb + DREF_F * ra;
            ra = ran; rb = rbn;
            uint64_t mball = __ballot(s != 0.0f);
            if (t >= tstart && lane == 0) sw[t - tstart][wv] = mball;
        }
    }
    __syncthreads();

    // ---- dense2 for my 50 t's (same order as old k5 -> bit-identical)
    if (tid < CLEN * NOUT) {                // 500 of 512
        const int tr = tid / NOUT;
        const int o = tid - tr * NOUT;
        const int t = tstart + tr;
        float acc = 0.f;
#pragma unroll
        for (int w2 = 0; w2 < NW64; ++w2) {
            uint64_t m = sw[tr][w2];
            while (m) {
                int j = __builtin_ctzll(m);
                m &= m - 1;
                acc += W2s[((w2 << 6) + j) * NOUT + o];
            }
        }
        const int bo = b * NOUT + o;
        z2ct[((size_t)(bo >> 6) * T_SZ + t) * 64 + (bo & 63)] = acc;
    }
}

// ---------------------------------------------------------------------------
// K6: fused psp-IIR + refractory scan, layer 2, chunked. Writes [B, NOUT, T].
__global__ __launch_bounds__(64) void k6_fir_scan2(const float* __restrict__ z2ct,
                                                   float* __restrict__ out) {
    const int lane = threadIdx.x;
    const int g = blockIdx.x / NCHUNK;    // bo group 0..4
    const int ck = blockIdx.x % NCHUNK;
    const int tstart = ck * CLEN;
    const int tend = tstart + CLEN;
    const int t0 = (tstart >= 100) ? tstart - 100 : 0;
    const int bo = (g << 6) + lane;       // 0..319
    const float* base = z2ct + (size_t)g * T_SZ * 64 + lane;
    float* op = out + (size_t)bo * T_SZ;
    double A = 0.0, Bs = 0.0, A2 = 0.0, Bs2 = 0.0;
    float ra = 0.0f, rb = 0.0f;
    const double TAIL = D100_D * CS_D;
    float xb[NPF], xdb[NPF];
#pragma unroll
    for (int i = 0; i < NPF; ++i) {
        int t = t0 + i;
        xb[i] = base[(size_t)t * 64];
        int td = t - 100;
        xdb[i] = (td >= 0) ? base[(size_t)td * 64] : 0.0f;
    }
    for (int tb = t0; tb < tend; tb += NPF) {
#pragma unroll
        for (int i = 0; i < NPF; ++i) {
            const int t = tb + i;
            float x = xb[i], xd = xdb[i];
            const int tn = t + NPF;
            xb[i] = (tn < T_SZ) ? base[(size_t)tn * 64] : 0.0f;
            const int td = tn - 100;
            xdb[i] = (td >= 0) ? base[(size_t)td * 64] : 0.0f;
            Bs = DS_D * Bs + DS_D * A;
            A = DS_D * A + (double)x;
            Bs2 = DS_D * Bs2 + DS_D * A2;
            A2 = DS_D * A2 + (double)xd;
            double y = CS_D * Bs - TAIL * (Bs2 + 100.0 * A2);
            float u = (float)y + CREF_F * rb;
            float s = (u >= 10.0f) ? 1.0f : 0.0f;
            float ran = DREF_F * ra + s;
            float rbn = DREF_F * rb + DREF_F * ra;
            ra = ran; rb = rbn;
            if (t >= tstart) op[t] = s;
        }
    }
}

// ---------------------------------------------------------------------------
extern "C" void kernel_launch(void* const* d_in, const int* in_sizes, int n_in,
                              void* d_out, int out_size, void* d_ws, size_t ws_size,
                              hipStream_t stream) {
    const float* spikeInput = (const float*)d_in[0];  // [32, 2312, 350]
    const float* W1 = (const float*)d_in[1];          // [512, 2312]
    const float* W2 = (const float*)d_in[2];          // [10, 512]
    float* out = (float*)d_out;                       // [32, 10, 350]

    char* ws = (char*)d_ws;
    float* W1s = (float*)(ws + 0);                        //  4,737,024 B (2313 rows x 2 halves)
    uint32_t* bits1 = (uint32_t*)(ws + 4737024);          //  3,270,400 B
    float* z1ct = (float*)(ws + 8007424);                 // 22,937,600 B
    // z2ct aliases bits1's region: bits1 is dead after k3, z2ct written by k45.
    float* z2ct = (float*)(ws + 4737024);                 //    448,000 B (alias)
    // total: 30,945,024 B

    k12<<<NW32 * B_SZ + NW32 * 16 + 1, 384, 0, stream>>>(spikeInput, W1, bits1, W1s);
    k3_dense1<<<B_SZ * T_SZ * 2, 256, 0, stream>>>(bits1, W1s, z1ct);
    // R15 ATTRIBUTION: k45 x2, k6 x4. Both are pure functions (z1ct->z2ct,
    // z2ct->out); duplicate runs write identical bytes -> bit-exact.
    // Aggregate delta vs 315.8us baseline = k45 + 3*k6 + launch gaps,
    // decomposing the ~214us of unattributed non-k3 time.
    k45<<<B_SZ * NCHUNK, 512, 0, stream>>>(z1ct, W2, z2ct);
    k45<<<B_SZ * NCHUNK, 512, 0, stream>>>(z1ct, W2, z2ct);
    k6_fir_scan2<<<5 * NCHUNK, 64, 0, stream>>>(z2ct, out);
    k6_fir_scan2<<<5 * NCHUNK, 64, 0, stream>>>(z2ct, out);
    k6_fir_scan2<<<5 * NCHUNK, 64, 0, stream>>>(z2ct, out);
    k6_fir_scan2<<<5 * NCHUNK, 64, 0, stream>>>(z2ct, out);
}

// Round 4
// 376.690 us; speedup vs baseline: 1.0847x; 1.0847x over previous
//
#include <hip/hip_runtime.h>
#include <stdint.h>

// Problem constants
#define B_SZ   32
#define NIN    2312
#define NHID   512
#define NOUT   10
#define T_SZ   350
#define NW32   73                 // ceil(2312/32) bitmask words per input column
#define NW64   8                  // 512/64 ballot words per hidden column
#define NHALF  256                // output half-width for L2-resident W1
#define NROW   2313               // NIN + 1 dummy zero row (branch-free padding)

// psp (SRM) kernel eps[n] = CS * n * DS^n, DS = exp(-0.1), CS = e/10
#define DS_D   0.9048374180359595
#define DS2_D  0.8187307530779818      // exp(-0.2)
#define DS3_D  0.7408182206817179      // exp(-0.3)
#define DS4_D  0.6703200460356393      // exp(-0.4)
#define CS_D   0.2718281828459045
#define D100_D 4.5399929762484854e-05   // exp(-10) = DS^100
// refractory recurrence in fp32, exactly like the reference scan
#define DREF_F 0.36787944117144233f     // exp(-1)
#define CREF_F -54.36563656918091f      // -2*10*e

// scan chunking (k45/k6): 7 chunks of 50.
// R16: psp state is LINEAR -> seeded directly by a 100-tap FIR dot product
// (4-way interleaved Horner, ILP-rich, no serial chain); only the refractory
// state needs a serial burn-in: BURN=40 steps from zero leaves error e^-40
// ~ 4e-18 in rb (u perturbed ~2e-16, vs ~1e-6 empirical threshold margin).
// Serial depth per chunk: 150 -> 90 steps.
#define NCHUNK 7
#define CLEN   50
#define BURN   40                 // refractory burn-in; (CLEN+BURN) % NPF == 0
#define NPF    10                 // ring depth

// ---------------------------------------------------------------------------
// K12: fused bitpack (blocks 0..2335) + W1 half-split pack (2336..3503) +
//      dummy-zero-row fill (block 3504). Bitpack float4 streaming.
__global__ __launch_bounds__(384) void k12(const float* __restrict__ x,
                                           const float* __restrict__ W1,
                                           uint32_t* __restrict__ bits1,
                                           float* __restrict__ W1s) {
    __shared__ float lds[32 * T_SZ];   // 44.8 KB
    const int bid = blockIdx.x;
    const int tid = threadIdx.x;
    if (bid < NW32 * B_SZ) {
        // --- bitpack: block = (b, w); contiguous rowsx350 tile -> LDS -> pack
        const int w = bid % NW32;
        const int b = bid / NW32;
        const int rows = (NIN - (w << 5) < 32) ? (NIN - (w << 5)) : 32;  // 32 or 8
        const float* base = x + ((size_t)(b * NIN + (w << 5))) * T_SZ;
        const int nf4 = (rows * T_SZ) >> 2;     // rows even -> divisible by 4
        for (int f = tid; f < nf4; f += 384)
            ((float4*)lds)[f] = ((const float4*)base)[f];
        __syncthreads();
        if (tid < T_SZ) {
            uint32_t bits = 0;
            for (int j = 0; j < rows; ++j)
                bits |= (lds[j * T_SZ + tid] > 0.5f) ? (1u << j) : 0u;
            bits1[(size_t)(b * T_SZ + tid) * NW32 + w] = bits;
        }
    } else if (bid < NW32 * B_SZ + NW32 * 16) {
        // --- pack W1 [512, 2312] -> W1s[h][i][256], h = o>>8
        float (*tile)[33] = (float (*)[33])lds;
        const int bb = bid - NW32 * B_SZ;
        const int i0 = (bb % NW32) * 32, o0 = (bb / NW32) * 32;
        const int tx = tid & 31, ty = tid >> 5;  // ty 0..11
#pragma unroll
        for (int r = 0; r < 3; ++r) {
            int row = ty + 12 * r;
            if (row < 32) {
                int o = o0 + row, i = i0 + tx;
                if (i < NIN) tile[row][tx] = W1[(size_t)o * NIN + i];
            }
        }
        __syncthreads();
#pragma unroll
        for (int r = 0; r < 3; ++r) {
            int row = ty + 12 * r;
            if (row < 32) {
                int i = i0 + row, o = o0 + tx;
                if (i < NIN)
                    W1s[((size_t)(o >> 8) * NROW + i) * NHALF + (o & 255)] = tile[tx][row];
            }
        }
    } else {
        // --- dummy zero row i = NIN for both halves
        if (tid < NHALF) {
            W1s[((size_t)0 * NROW + NIN) * NHALF + tid] = 0.0f;
            W1s[((size_t)1 * NROW + NIN) * NHALF + tid] = 0.0f;
        }
    }
}

// ---------------------------------------------------------------------------
// K3: sparse dense1 (R6/R10 gather form — the measured optimum: 101us,
// 26.3 TB/s L2-gather = 76% of streaming ubench). Half-split for L2
// residency; single-wave shfl prefix scan; branch-free 4-deep pipelined row
// loop via dummy zero-row padding. Batching/LDS-staging variants all lose
// (R7/R8/R9/R11/R12 post-mortems): VALU/divergence tax > traffic savings.
// R13: L2-HIT-SERVICE-RATE bound (FETCH halved, time flat) -> structural
// ceiling given the bit-exact sum order. Do not touch.
__global__ __launch_bounds__(256) void k3_dense1(const uint32_t* __restrict__ bits1,
                                                 const float* __restrict__ W1s,
                                                 float* __restrict__ z1ct) {
    __shared__ uint32_t words[128];
    __shared__ uint16_t pfx[80];
    __shared__ uint16_t idxbuf[NIN + 16];
    __shared__ float red[3][NHALF];
    __shared__ float fin[NHALF];

    const int id = blockIdx.x;
    const int h = (id >> 2) & 1;                  // XCD-affine half select
    const int bt = ((id >> 3) << 2) | (id & 3);   // b*350 + t (bijective)
    const int tid = threadIdx.x;
    const int wv = tid >> 6, lane = tid & 63;

    if (tid < 128) words[tid] = (tid < NW32) ? bits1[(size_t)bt * NW32 + tid] : 0u;
    __syncthreads();

    if (wv == 0) {
        uint32_t w0 = words[lane];
        uint32_t w1 = words[lane + 64];
        int p0 = __popc(w0), p1 = __popc(w1);
        int s0 = p0, s1 = p1;
#pragma unroll
        for (int off = 1; off < 64; off <<= 1) {
            int u0 = __shfl_up(s0, off);
            int u1 = __shfl_up(s1, off);
            if (lane >= off) { s0 += u0; s1 += u1; }
        }
        int tot0 = __shfl(s0, 63);
        pfx[lane] = (uint16_t)(s0 - p0);
        if (lane < 9) pfx[lane + 64] = (uint16_t)(tot0 + s1 - p1);
        if (lane == 8) pfx[73] = (uint16_t)(tot0 + s1);   // ntot
    }
    __syncthreads();

    const int ntot = pfx[73];
    const int npad = (ntot + 15) & ~15;
    if (tid < NW32) {
        uint32_t m = words[tid];
        int p = pfx[tid];
        while (m) {
            int j = __builtin_ctz(m);
            m &= m - 1;
            idxbuf[p++] = (uint16_t)((tid << 5) + j);
        }
    }
    if (tid >= 240) {                   // pad to multiple of 16 with zero row
        int k = tid - 240;
        if (ntot + k < npad) idxbuf[ntot + k] = (uint16_t)NIN;
    }
    __syncthreads();

    const float* Wh = W1s + (size_t)h * NROW * NHALF;
    float4 acc = make_float4(0.f, 0.f, 0.f, 0.f);
    for (int r = wv; r < npad; r += 16) {
        int i0 = idxbuf[r], i1 = idxbuf[r + 4], i2 = idxbuf[r + 8], i3 = idxbuf[r + 12];
        float4 v0 = ((const float4*)(Wh + (size_t)i0 * NHALF))[lane];
        float4 v1 = ((const float4*)(Wh + (size_t)i1 * NHALF))[lane];
        float4 v2 = ((const float4*)(Wh + (size_t)i2 * NHALF))[lane];
        float4 v3 = ((const float4*)(Wh + (size_t)i3 * NHALF))[lane];
        acc.x += v0.x; acc.y += v0.y; acc.z += v0.z; acc.w += v0.w;
        acc.x += v1.x; acc.y += v1.y; acc.z += v1.z; acc.w += v1.w;
        acc.x += v2.x; acc.y += v2.y; acc.z += v2.z; acc.w += v2.w;
        acc.x += v3.x; acc.y += v3.y; acc.z += v3.z; acc.w += v3.w;
    }
    if (wv > 0) ((float4*)red[wv - 1])[lane] = acc;
    __syncthreads();
    if (wv == 0) {
        float4 a1 = ((float4*)red[0])[lane];
        float4 a2 = ((float4*)red[1])[lane];
        float4 a3 = ((float4*)red[2])[lane];
        acc.x = ((acc.x + a1.x) + a2.x) + a3.x;
        acc.y = ((acc.y + a1.y) + a2.y) + a3.y;
        acc.z = ((acc.z + a1.z) + a2.z) + a3.z;
        acc.w = ((acc.w + a1.w) + a2.w) + a3.w;
        ((float4*)fin)[lane] = acc;
    }
    __syncthreads();
    const int och = (h << 8) + tid;
    const int oc = och >> 6, l6 = och & 63;
    const int b = bt / T_SZ, t = bt - b * T_SZ;
    z1ct[((size_t)(b * NW64 + oc) * T_SZ + t) * 64 + l6] = fin[tid];
}

// ---------------------------------------------------------------------------
// K45: fused layer-1 scan + dense2. Block = (b, chunk), 512 threads = 8 waves;
// wave wv scans channels wv*64..+63, ballots into LDS; then 500 (t,o) pairs
// compute z2 in the same wv/ctz-ascending order.
// R16: serial warm-up (100 steps) replaced by direct FIR seed + BURN=40
// refractory burn-in -> 90 serial steps/chunk instead of 150.
// Seed math: after processing t=hi, the IIR state is
//   A(hi)  = sum_{j=0..99} DS^j x(hi-j),  Bs(hi) = sum_j j*DS^j x(hi-j)
// computed as 4 interleaved Horner chains (step DS^4, combine with DS^r):
//   A = sum_r DS^r * F_r,  Bs = sum_r DS^r * (r*F_r + 4*G_r).
// (A2,Bs2) = same windows at hi-100 (the delayed xd stream). Different
// double-rounding order than the IIR (~1e-15 rel) — far inside the ~1e-6
// empirical threshold margin the double-vs-f32-reference slack already uses.
__global__ __launch_bounds__(512) void k45(const float* __restrict__ z1ct,
                                           const float* __restrict__ W2,
                                           float* __restrict__ z2ct) {
    __shared__ float W2s[NHID * NOUT];      // [c][o], 20 KB
    __shared__ uint64_t sw[CLEN][NW64];     // s1 ballot words for my 50 t's
    const int tid = threadIdx.x;
    const int wv = tid >> 6, lane = tid & 63;
    const int b = blockIdx.x / NCHUNK;
    const int ck = blockIdx.x % NCHUNK;
    const int tstart = ck * CLEN;
    const int tend = tstart + CLEN;
    const int t0 = (ck == 0) ? 0 : tstart - BURN;

    for (int k = tid; k < NHID * NOUT; k += 512) {
        int c = k / NOUT, o = k - c * NOUT;
        W2s[k] = W2[(size_t)o * NHID + c];
    }

    const float* base = z1ct + (size_t)(b * NW64 + wv) * T_SZ * 64 + lane;
    double A = 0.0, Bs = 0.0, A2 = 0.0, Bs2 = 0.0;
    float ra = 0.0f, rb = 0.0f;
    const double TAIL = D100_D * CS_D;

    if (ck != 0) {
        // ---- direct 100-tap FIR seed of state-after-(t0-1)
        const int hi1 = t0 - 1;        // window for (A, Bs)
        const int hi2 = t0 - 101;      // window for (A2, Bs2): xd = x(t-100)
        double F0=0,F1=0,F2=0,F3=0, G0=0,G1=0,G2=0,G3=0;
        double P0=0,P1=0,P2=0,P3=0, Q0=0,Q1=0,Q2=0,Q3=0;
#pragma unroll
        for (int q = 0; q < 25; ++q) {
            // window 1, chains r=3..0 (tap j = 99-4q-(3-r) ... ascending t)
            const int ta3 = hi1 - 99 + 4 * q;
            float x3 = 0.f, x2 = 0.f, x1 = 0.f, x0 = 0.f;
            if (ta3     >= 0) x3 = base[(size_t)(ta3    ) * 64];
            if (ta3 + 1 >= 0) x2 = base[(size_t)(ta3 + 1) * 64];
            if (ta3 + 2 >= 0) x1 = base[(size_t)(ta3 + 2) * 64];
            if (ta3 + 3 >= 0) x0 = base[(size_t)(ta3 + 3) * 64];
            G3 = DS4_D * G3 + DS4_D * F3; F3 = DS4_D * F3 + (double)x3;
            G2 = DS4_D * G2 + DS4_D * F2; F2 = DS4_D * F2 + (double)x2;
            G1 = DS4_D * G1 + DS4_D * F1; F1 = DS4_D * F1 + (double)x1;
            G0 = DS4_D * G0 + DS4_D * F0; F0 = DS4_D * F0 + (double)x0;
            // window 2 (delayed stream)
            const int tb3 = hi2 - 99 + 4 * q;
            float y3 = 0.f, y2 = 0.f, y1 = 0.f, y0 = 0.f;
            if (tb3     >= 0) y3 = base[(size_t)(tb3    ) * 64];
            if (tb3 + 1 >= 0) y2 = base[(size_t)(tb3 + 1) * 64];
            if (tb3 + 2 >= 0) y1 = base[(size_t)(tb3 + 2) * 64];
            if (tb3 + 3 >= 0) y0 = base[(size_t)(tb3 + 3) * 64];
            Q3 = DS4_D * Q3 + DS4_D * P3; P3 = DS4_D * P3 + (double)y3;
            Q2 = DS4_D * Q2 + DS4_D * P2; P2 = DS4_D * P2 + (double)y2;
            Q1 = DS4_D * Q1 + DS4_D * P1; P1 = DS4_D * P1 + (double)y1;
            Q0 = DS4_D * Q0 + DS4_D * P0; P0 = DS4_D * P0 + (double)y0;
        }
        A   = F0 + DS_D * F1 + DS2_D * F2 + DS3_D * F3;
        Bs  = 4.0 * G0 + DS_D * (F1 + 4.0 * G1)
            + DS2_D * (2.0 * F2 + 4.0 * G2) + DS3_D * (3.0 * F3 + 4.0 * G3);
        A2  = P0 + DS_D * P1 + DS2_D * P2 + DS3_D * P3;
        Bs2 = 4.0 * Q0 + DS_D * (P1 + 4.0 * Q1)
            + DS2_D * (2.0 * P2 + 4.0 * Q2) + DS3_D * (3.0 * P3 + 4.0 * Q3);
    }

    // ---- scan: burn-in (BURN steps, refractory settling) + emitted chunk
    float xb[NPF], xdb[NPF];
#pragma unroll
    for (int i = 0; i < NPF; ++i) {
        int t = t0 + i;
        xb[i] = base[(size_t)t * 64];
        int td = t - 100;
        xdb[i] = (td >= 0) ? base[(size_t)td * 64] : 0.0f;
    }
    for (int tb = t0; tb < tend; tb += NPF) {
#pragma unroll
        for (int i = 0; i < NPF; ++i) {
            const int t = tb + i;
            float x = xb[i], xd = xdb[i];
            const int tn = t + NPF;
            xb[i] = (tn < T_SZ) ? base[(size_t)tn * 64] : 0.0f;
            const int td = tn - 100;
            xdb[i] = (td >= 0) ? base[(size_t)td * 64] : 0.0f;
            Bs = DS_D * Bs + DS_D * A;
            A = DS_D * A + (double)x;
            Bs2 = DS_D * Bs2 + DS_D * A2;
            A2 = DS_D * A2 + (double)xd;
            double y = CS_D * Bs - TAIL * (Bs2 + 100.0 * A2);
            float u = (float)y + CREF_F * rb;
            float s = (u >= 10.0f) ? 1.0f : 0.0f;
            float ran = DREF_F * ra + s;
            float rbn = DREF_F * rb + DREF_F * ra;
            ra = ran; rb = rbn;
            uint64_t mball = __ballot(s != 0.0f);
            if (t >= tstart && lane == 0) sw[t - tstart][wv] = mball;
        }
    }
    __syncthreads();

    // ---- dense2 for my 50 t's (same order as before -> bit-identical)
    if (tid < CLEN * NOUT) {                // 500 of 512
        const int tr = tid / NOUT;
        const int o = tid - tr * NOUT;
        const int t = tstart + tr;
        float acc = 0.f;
#pragma unroll
        for (int w2 = 0; w2 < NW64; ++w2) {
            uint64_t m = sw[tr][w2];
            while (m) {
                int j = __builtin_ctzll(m);
                m &= m - 1;
                acc += W2s[((w2 << 6) + j) * NOUT + o];
            }
        }
        const int bo = b * NOUT + o;
        z2ct[((size_t)(bo >> 6) * T_SZ + t) * 64 + (bo & 63)] = acc;
    }
}

// ---------------------------------------------------------------------------
// K6: fused psp-IIR + refractory scan, layer 2, chunked. Writes [B, NOUT, T].
// (Unchanged this round; ~8-12us by R15 attribution — next in line after k45.)
__global__ __launch_bounds__(64) void k6_fir_scan2(const float* __restrict__ z2ct,
                                                   float* __restrict__ out) {
    const int lane = threadIdx.x;
    const int g = blockIdx.x / NCHUNK;    // bo group 0..4
    const int ck = blockIdx.x % NCHUNK;
    const int tstart = ck * CLEN;
    const int tend = tstart + CLEN;
    const int t0 = (tstart >= 100) ? tstart - 100 : 0;
    const int bo = (g << 6) + lane;       // 0..319
    const float* base = z2ct + (size_t)g * T_SZ * 64 + lane;
    float* op = out + (size_t)bo * T_SZ;
    double A = 0.0, Bs = 0.0, A2 = 0.0, Bs2 = 0.0;
    float ra = 0.0f, rb = 0.0f;
    const double TAIL = D100_D * CS_D;
    float xb[NPF], xdb[NPF];
#pragma unroll
    for (int i = 0; i < NPF; ++i) {
        int t = t0 + i;
        xb[i] = base[(size_t)t * 64];
        int td = t - 100;
        xdb[i] = (td >= 0) ? base[(size_t)td * 64] : 0.0f;
    }
    for (int tb = t0; tb < tend; tb += NPF) {
#pragma unroll
        for (int i = 0; i < NPF; ++i) {
            const int t = tb + i;
            float x = xb[i], xd = xdb[i];
            const int tn = t + NPF;
            xb[i] = (tn < T_SZ) ? base[(size_t)tn * 64] : 0.0f;
            const int td = tn - 100;
            xdb[i] = (td >= 0) ? base[(size_t)td * 64] : 0.0f;
            Bs = DS_D * Bs + DS_D * A;
            A = DS_D * A + (double)x;
            Bs2 = DS_D * Bs2 + DS_D * A2;
            A2 = DS_D * A2 + (double)xd;
            double y = CS_D * Bs - TAIL * (Bs2 + 100.0 * A2);
            float u = (float)y + CREF_F * rb;
            float s = (u >= 10.0f) ? 1.0f : 0.0f;
            float ran = DREF_F * ra + s;
            float rbn = DREF_F * rb + DREF_F * ra;
            ra = ran; rb = rbn;
            if (t >= tstart) op[t] = s;
        }
    }
}

// ---------------------------------------------------------------------------
extern "C" void kernel_launch(void* const* d_in, const int* in_sizes, int n_in,
                              void* d_out, int out_size, void* d_ws, size_t ws_size,
                              hipStream_t stream) {
    const float* spikeInput = (const float*)d_in[0];  // [32, 2312, 350]
    const float* W1 = (const float*)d_in[1];          // [512, 2312]
    const float* W2 = (const float*)d_in[2];          // [10, 512]
    float* out = (float*)d_out;                       // [32, 10, 350]

    char* ws = (char*)d_ws;
    float* W1s = (float*)(ws + 0);                        //  4,737,024 B (2313 rows x 2 halves)
    uint32_t* bits1 = (uint32_t*)(ws + 4737024);          //  3,270,400 B
    float* z1ct = (float*)(ws + 8007424);                 // 22,937,600 B
    // z2ct aliases bits1's region: bits1 is dead after k3, z2ct written by k45.
    float* z2ct = (float*)(ws + 4737024);                 //    448,000 B (alias)
    // total: 30,945,024 B

    k12<<<NW32 * B_SZ + NW32 * 16 + 1, 384, 0, stream>>>(spikeInput, W1, bits1, W1s);
    k3_dense1<<<B_SZ * T_SZ * 2, 256, 0, stream>>>(bits1, W1s, z1ct);
    k45<<<B_SZ * NCHUNK, 512, 0, stream>>>(z1ct, W2, z2ct);
    k6_fir_scan2<<<5 * NCHUNK, 64, 0, stream>>>(z2ct, out);
}

// Round 5
// 332.463 us; speedup vs baseline: 1.2290x; 1.1330x over previous
//
#include <hip/hip_runtime.h>
#include <stdint.h>

// Problem constants
#define B_SZ   32
#define NIN    2312
#define NHID   512
#define NOUT   10
#define T_SZ   350
#define NW32   73                 // ceil(2312/32) bitmask words per input column
#define NW64   8                  // 512/64 ballot words per hidden column
#define NHALF  256                // output half-width for L2-resident W1
#define NROW   2313               // NIN + 1 dummy zero row (branch-free padding)

// psp (SRM) kernel eps[n] = CS * n * DS^n, DS = exp(-0.1), CS = e/10
#define DS_D   0.9048374180359595
#define CS_D   0.2718281828459045
#define D100_D 4.5399929762484854e-05   // exp(-10) = DS^100
// refractory recurrence in fp32, exactly like the reference scan
#define DREF_F 0.36787944117144233f     // exp(-1)
#define CREF_F -54.36563656918091f      // -2*10*e

// k5/k6 chunking: 7 chunks of 50 (k6 keeps the R1-proven warm-start form).
#define NCHUNK 7
#define CLEN   50
#define NPF    10                 // k6 ring depth
#define SNPF   14                 // k4 ring depth; 350 = 25*14 exactly

// ---------------------------------------------------------------------------
// K12: fused bitpack (blocks 0..2335) + W1 half-split pack (2336..3503) +
//      dummy-zero-row fill (block 3504). Bitpack float4 streaming.
__global__ __launch_bounds__(384) void k12(const float* __restrict__ x,
                                           const float* __restrict__ W1,
                                           uint32_t* __restrict__ bits1,
                                           float* __restrict__ W1s) {
    __shared__ float lds[32 * T_SZ];   // 44.8 KB
    const int bid = blockIdx.x;
    const int tid = threadIdx.x;
    if (bid < NW32 * B_SZ) {
        // --- bitpack: block = (b, w); contiguous rowsx350 tile -> LDS -> pack
        const int w = bid % NW32;
        const int b = bid / NW32;
        const int rows = (NIN - (w << 5) < 32) ? (NIN - (w << 5)) : 32;  // 32 or 8
        const float* base = x + ((size_t)(b * NIN + (w << 5))) * T_SZ;
        const int nf4 = (rows * T_SZ) >> 2;     // rows even -> divisible by 4
        for (int f = tid; f < nf4; f += 384)
            ((float4*)lds)[f] = ((const float4*)base)[f];
        __syncthreads();
        if (tid < T_SZ) {
            uint32_t bits = 0;
            for (int j = 0; j < rows; ++j)
                bits |= (lds[j * T_SZ + tid] > 0.5f) ? (1u << j) : 0u;
            bits1[(size_t)(b * T_SZ + tid) * NW32 + w] = bits;
        }
    } else if (bid < NW32 * B_SZ + NW32 * 16) {
        // --- pack W1 [512, 2312] -> W1s[h][i][256], h = o>>8
        float (*tile)[33] = (float (*)[33])lds;
        const int bb = bid - NW32 * B_SZ;
        const int i0 = (bb % NW32) * 32, o0 = (bb / NW32) * 32;
        const int tx = tid & 31, ty = tid >> 5;  // ty 0..11
#pragma unroll
        for (int r = 0; r < 3; ++r) {
            int row = ty + 12 * r;
            if (row < 32) {
                int o = o0 + row, i = i0 + tx;
                if (i < NIN) tile[row][tx] = W1[(size_t)o * NIN + i];
            }
        }
        __syncthreads();
#pragma unroll
        for (int r = 0; r < 3; ++r) {
            int row = ty + 12 * r;
            if (row < 32) {
                int i = i0 + row, o = o0 + tx;
                if (i < NIN)
                    W1s[((size_t)(o >> 8) * NROW + i) * NHALF + (o & 255)] = tile[tx][row];
            }
        }
    } else {
        // --- dummy zero row i = NIN for both halves
        if (tid < NHALF) {
            W1s[((size_t)0 * NROW + NIN) * NHALF + tid] = 0.0f;
            W1s[((size_t)1 * NROW + NIN) * NHALF + tid] = 0.0f;
        }
    }
}

// ---------------------------------------------------------------------------
// K3: sparse dense1 (R6/R10 gather form — the measured optimum: 101us,
// 26.3 TB/s L2-gather = 76% of streaming ubench). Half-split for L2
// residency; single-wave shfl prefix scan; branch-free 4-deep pipelined row
// loop via dummy zero-row padding. Batching/LDS-staging variants all lose
// (R7/R8/R9/R11/R12 post-mortems): VALU/divergence tax > traffic savings.
// R13: L2-HIT-SERVICE-RATE bound (FETCH halved, time flat) -> structural
// ceiling given the bit-exact sum order. Do not touch.
__global__ __launch_bounds__(256) void k3_dense1(const uint32_t* __restrict__ bits1,
                                                 const float* __restrict__ W1s,
                                                 float* __restrict__ z1ct) {
    __shared__ uint32_t words[128];
    __shared__ uint16_t pfx[80];
    __shared__ uint16_t idxbuf[NIN + 16];
    __shared__ float red[3][NHALF];
    __shared__ float fin[NHALF];

    const int id = blockIdx.x;
    const int h = (id >> 2) & 1;                  // XCD-affine half select
    const int bt = ((id >> 3) << 2) | (id & 3);   // b*350 + t (bijective)
    const int tid = threadIdx.x;
    const int wv = tid >> 6, lane = tid & 63;

    if (tid < 128) words[tid] = (tid < NW32) ? bits1[(size_t)bt * NW32 + tid] : 0u;
    __syncthreads();

    if (wv == 0) {
        uint32_t w0 = words[lane];
        uint32_t w1 = words[lane + 64];
        int p0 = __popc(w0), p1 = __popc(w1);
        int s0 = p0, s1 = p1;
#pragma unroll
        for (int off = 1; off < 64; off <<= 1) {
            int u0 = __shfl_up(s0, off);
            int u1 = __shfl_up(s1, off);
            if (lane >= off) { s0 += u0; s1 += u1; }
        }
        int tot0 = __shfl(s0, 63);
        pfx[lane] = (uint16_t)(s0 - p0);
        if (lane < 9) pfx[lane + 64] = (uint16_t)(tot0 + s1 - p1);
        if (lane == 8) pfx[73] = (uint16_t)(tot0 + s1);   // ntot
    }
    __syncthreads();

    const int ntot = pfx[73];
    const int npad = (ntot + 15) & ~15;
    if (tid < NW32) {
        uint32_t m = words[tid];
        int p = pfx[tid];
        while (m) {
            int j = __builtin_ctz(m);
            m &= m - 1;
            idxbuf[p++] = (uint16_t)((tid << 5) + j);
        }
    }
    if (tid >= 240) {                   // pad to multiple of 16 with zero row
        int k = tid - 240;
        if (ntot + k < npad) idxbuf[ntot + k] = (uint16_t)NIN;
    }
    __syncthreads();

    const float* Wh = W1s + (size_t)h * NROW * NHALF;
    float4 acc = make_float4(0.f, 0.f, 0.f, 0.f);
    for (int r = wv; r < npad; r += 16) {
        int i0 = idxbuf[r], i1 = idxbuf[r + 4], i2 = idxbuf[r + 8], i3 = idxbuf[r + 12];
        float4 v0 = ((const float4*)(Wh + (size_t)i0 * NHALF))[lane];
        float4 v1 = ((const float4*)(Wh + (size_t)i1 * NHALF))[lane];
        float4 v2 = ((const float4*)(Wh + (size_t)i2 * NHALF))[lane];
        float4 v3 = ((const float4*)(Wh + (size_t)i3 * NHALF))[lane];
        acc.x += v0.x; acc.y += v0.y; acc.z += v0.z; acc.w += v0.w;
        acc.x += v1.x; acc.y += v1.y; acc.z += v1.z; acc.w += v1.w;
        acc.x += v2.x; acc.y += v2.y; acc.z += v2.z; acc.w += v2.w;
        acc.x += v3.x; acc.y += v3.y; acc.z += v3.z; acc.w += v3.w;
    }
    if (wv > 0) ((float4*)red[wv - 1])[lane] = acc;
    __syncthreads();
    if (wv == 0) {
        float4 a1 = ((float4*)red[0])[lane];
        float4 a2 = ((float4*)red[1])[lane];
        float4 a3 = ((float4*)red[2])[lane];
        acc.x = ((acc.x + a1.x) + a2.x) + a3.x;
        acc.y = ((acc.y + a1.y) + a2.y) + a3.y;
        acc.z = ((acc.z + a1.z) + a2.z) + a3.z;
        acc.w = ((acc.w + a1.w) + a2.w) + a3.w;
        ((float4*)fin)[lane] = acc;
    }
    __syncthreads();
    const int och = (h << 8) + tid;
    const int oc = och >> 6, l6 = och & 63;
    const int b = bt / T_SZ, t = bt - b * T_SZ;
    z1ct[((size_t)(b * NW64 + oc) * T_SZ + t) * 64 + l6] = fin[tid];
}

// ---------------------------------------------------------------------------
// K4: layer-1 scan, DE-FUSED (R17). R16 post-mortem: the FIR seed regressed
// k45 55->103us (200 serially-consumed loads with no co-resident waves to
// hide them); counters showed k45 was latency-bound at 14% occupancy with 4x
// warm-up re-read traffic (FETCH 88MB vs 22.9MB array). Both the warm-up and
// the 224-block grid existed only because dense2's fusion forced all 512
// channels into one block. De-fused: block = (b, group) = 256 x 64thr; full
// T=350 scan from t=0 -> ZERO warm-up (exactly the reference recurrence, no
// approximation), compulsory-only traffic, SNPF=14 load ring. Ballots to a
// 717KB global buffer (dead-bits1 alias region).
__global__ __launch_bounds__(64) void k4_scan1(const float* __restrict__ z1ct,
                                               uint64_t* __restrict__ ballots) {
    const int lane = threadIdx.x;
    const int bg = blockIdx.x;                  // b*8 + g
    const float* base = z1ct + (size_t)bg * T_SZ * 64 + lane;
    const int b = bg >> 3, g = bg & 7;
    uint64_t* bout = ballots + (size_t)b * T_SZ * NW64 + g;

    double A = 0.0, Bs = 0.0, A2 = 0.0, Bs2 = 0.0;
    float ra = 0.0f, rb = 0.0f;
    const double TAIL = D100_D * CS_D;
    float xb[SNPF], xdb[SNPF];
#pragma unroll
    for (int i = 0; i < SNPF; ++i) {
        xb[i] = base[(size_t)i * 64];
        xdb[i] = 0.0f;                          // t-100 < 0 for t < SNPF
    }
    for (int tb = 0; tb < T_SZ; tb += SNPF) {
#pragma unroll
        for (int i = 0; i < SNPF; ++i) {
            const int t = tb + i;
            float x = xb[i], xd = xdb[i];
            const int tn = t + SNPF;
            xb[i] = (tn < T_SZ) ? base[(size_t)tn * 64] : 0.0f;
            const int td = tn - 100;
            xdb[i] = (td >= 0) ? base[(size_t)td * 64] : 0.0f;
            Bs = DS_D * Bs + DS_D * A;
            A = DS_D * A + (double)x;
            Bs2 = DS_D * Bs2 + DS_D * A2;
            A2 = DS_D * A2 + (double)xd;
            double y = CS_D * Bs - TAIL * (Bs2 + 100.0 * A2);
            float u = (float)y + CREF_F * rb;
            float s = (u >= 10.0f) ? 1.0f : 0.0f;
            float ran = DREF_F * ra + s;
            float rbn = DREF_F * rb + DREF_F * ra;
            ra = ran; rb = rbn;
            uint64_t mball = __ballot(s != 0.0f);
            if (lane == 0) bout[(size_t)t * NW64] = mball;
        }
    }
}

// ---------------------------------------------------------------------------
// K5: dense2 from global ballots. Same (b, 50-t-chunk) grid, same thread
// mapping, same w2-ascending/ctz-ascending accumulation order as the old
// fused dense2 -> z2ct bytes identical.
__global__ __launch_bounds__(512) void k5_dense2(const uint64_t* __restrict__ ballots,
                                                 const float* __restrict__ W2,
                                                 float* __restrict__ z2ct) {
    __shared__ float W2s[NHID * NOUT];      // [c][o], 20 KB
    __shared__ uint64_t sw[CLEN][NW64];
    const int tid = threadIdx.x;
    const int b = blockIdx.x / NCHUNK;
    const int ck = blockIdx.x % NCHUNK;
    const int tstart = ck * CLEN;

    for (int k = tid; k < NHID * NOUT; k += 512) {
        int c = k / NOUT, o = k - c * NOUT;
        W2s[k] = W2[(size_t)o * NHID + c];
    }
    if (tid < CLEN * NW64) {                // 400 of 512
        const int tr = tid >> 3, g = tid & 7;
        sw[tr][g] = ballots[((size_t)(b * T_SZ + tstart + tr)) * NW64 + g];
    }
    __syncthreads();

    if (tid < CLEN * NOUT) {                // 500 of 512
        const int tr = tid / NOUT;
        const int o = tid - tr * NOUT;
        const int t = tstart + tr;
        float acc = 0.f;
#pragma unroll
        for (int w2 = 0; w2 < NW64; ++w2) {
            uint64_t m = sw[tr][w2];
            while (m) {
                int j = __builtin_ctzll(m);
                m &= m - 1;
                acc += W2s[((w2 << 6) + j) * NOUT + o];
            }
        }
        const int bo = b * NOUT + o;
        z2ct[((size_t)(bo >> 6) * T_SZ + t) * 64 + (bo & 63)] = acc;
    }
}

// ---------------------------------------------------------------------------
// K6: fused psp-IIR + refractory scan, layer 2, chunked (R1-proven form).
__global__ __launch_bounds__(64) void k6_fir_scan2(const float* __restrict__ z2ct,
                                                   float* __restrict__ out) {
    const int lane = threadIdx.x;
    const int g = blockIdx.x / NCHUNK;    // bo group 0..4
    const int ck = blockIdx.x % NCHUNK;
    const int tstart = ck * CLEN;
    const int tend = tstart + CLEN;
    const int t0 = (tstart >= 100) ? tstart - 100 : 0;
    const int bo = (g << 6) + lane;       // 0..319
    const float* base = z2ct + (size_t)g * T_SZ * 64 + lane;
    float* op = out + (size_t)bo * T_SZ;
    double A = 0.0, Bs = 0.0, A2 = 0.0, Bs2 = 0.0;
    float ra = 0.0f, rb = 0.0f;
    const double TAIL = D100_D * CS_D;
    float xb[NPF], xdb[NPF];
#pragma unroll
    for (int i = 0; i < NPF; ++i) {
        int t = t0 + i;
        xb[i] = base[(size_t)t * 64];
        int td = t - 100;
        xdb[i] = (td >= 0) ? base[(size_t)td * 64] : 0.0f;
    }
    for (int tb = t0; tb < tend; tb += NPF) {
#pragma unroll
        for (int i = 0; i < NPF; ++i) {
            const int t = tb + i;
            float x = xb[i], xd = xdb[i];
            const int tn = t + NPF;
            xb[i] = (tn < T_SZ) ? base[(size_t)tn * 64] : 0.0f;
            const int td = tn - 100;
            xdb[i] = (td >= 0) ? base[(size_t)td * 64] : 0.0f;
            Bs = DS_D * Bs + DS_D * A;
            A = DS_D * A + (double)x;
            Bs2 = DS_D * Bs2 + DS_D * A2;
            A2 = DS_D * A2 + (double)xd;
            double y = CS_D * Bs - TAIL * (Bs2 + 100.0 * A2);
            float u = (float)y + CREF_F * rb;
            float s = (u >= 10.0f) ? 1.0f : 0.0f;
            float ran = DREF_F * ra + s;
            float rbn = DREF_F * rb + DREF_F * ra;
            ra = ran; rb = rbn;
            if (t >= tstart) op[t] = s;
        }
    }
}

// ---------------------------------------------------------------------------
extern "C" void kernel_launch(void* const* d_in, const int* in_sizes, int n_in,
                              void* d_out, int out_size, void* d_ws, size_t ws_size,
                              hipStream_t stream) {
    const float* spikeInput = (const float*)d_in[0];  // [32, 2312, 350]
    const float* W1 = (const float*)d_in[1];          // [512, 2312]
    const float* W2 = (const float*)d_in[2];          // [10, 512]
    float* out = (float*)d_out;                       // [32, 10, 350]

    char* ws = (char*)d_ws;
    float* W1s = (float*)(ws + 0);                        //  4,737,024 B (2313 rows x 2 halves)
    uint32_t* bits1 = (uint32_t*)(ws + 4737024);          //  3,270,400 B
    float* z1ct = (float*)(ws + 8007424);                 // 22,937,600 B
    // Aliases into bits1's region (bits1 dead after k3):
    //   z2ct    @ +4,737,024 (448,000 B), written by k5, read by k6
    //   ballots @ +5,185,024 (716,800 B), written by k4, read by k5
    // 5,185,024 + 716,800 = 5,901,824 <= 8,007,424 (fits). Total unchanged.
    float* z2ct = (float*)(ws + 4737024);
    uint64_t* ballots = (uint64_t*)(ws + 5185024);
    // total high-water: 30,945,024 B

    k12<<<NW32 * B_SZ + NW32 * 16 + 1, 384, 0, stream>>>(spikeInput, W1, bits1, W1s);
    k3_dense1<<<B_SZ * T_SZ * 2, 256, 0, stream>>>(bits1, W1s, z1ct);
    k4_scan1<<<B_SZ * NW64, 64, 0, stream>>>(z1ct, ballots);
    k5_dense2<<<B_SZ * NCHUNK, 512, 0, stream>>>(ballots, W2, z2ct);
    k6_fir_scan2<<<5 * NCHUNK, 64, 0, stream>>>(z2ct, out);
}

// Round 6
// 325.813 us; speedup vs baseline: 1.2540x; 1.0204x over previous
//
#include <hip/hip_runtime.h>
#include <stdint.h>

// Problem constants
#define B_SZ   32
#define NIN    2312
#define NHID   512
#define NOUT   10
#define T_SZ   350
#define NW32   73                 // ceil(2312/32) bitmask words per input column
#define NW64   8                  // 512/64 ballot words per hidden column
#define NHALF  256                // output half-width for L2-resident W1
#define NROW   2313               // NIN + 1 dummy zero row (branch-free padding)

// psp (SRM) kernel eps[n] = CS * n * DS^n, DS = exp(-0.1), CS = e/10
#define DS_D   0.9048374180359595
#define CS_D   0.2718281828459045
#define D100_D 4.5399929762484854e-05   // exp(-10) = DS^100
// refractory recurrence in fp32, exactly like the reference scan
#define DREF_F 0.36787944117144233f     // exp(-1)
#define CREF_F -54.36563656918091f      // -2*10*e

// k5 chunking only (k4/k6 scan full T with zero warm-up).
#define NCHUNK 7
#define CLEN   50
#define SNPF   14                 // scan ring depth; 350 = 25*14 exactly

// ---------------------------------------------------------------------------
// K12: fused bitpack (blocks 0..2335) + W1 half-split pack (2336..3503) +
//      dummy-zero-row fill (block 3504). Bitpack float4 streaming.
__global__ __launch_bounds__(384) void k12(const float* __restrict__ x,
                                           const float* __restrict__ W1,
                                           uint32_t* __restrict__ bits1,
                                           float* __restrict__ W1s) {
    __shared__ float lds[32 * T_SZ];   // 44.8 KB
    const int bid = blockIdx.x;
    const int tid = threadIdx.x;
    if (bid < NW32 * B_SZ) {
        // --- bitpack: block = (b, w); contiguous rowsx350 tile -> LDS -> pack
        const int w = bid % NW32;
        const int b = bid / NW32;
        const int rows = (NIN - (w << 5) < 32) ? (NIN - (w << 5)) : 32;  // 32 or 8
        const float* base = x + ((size_t)(b * NIN + (w << 5))) * T_SZ;
        const int nf4 = (rows * T_SZ) >> 2;     // rows even -> divisible by 4
        for (int f = tid; f < nf4; f += 384)
            ((float4*)lds)[f] = ((const float4*)base)[f];
        __syncthreads();
        if (tid < T_SZ) {
            uint32_t bits = 0;
            for (int j = 0; j < rows; ++j)
                bits |= (lds[j * T_SZ + tid] > 0.5f) ? (1u << j) : 0u;
            bits1[(size_t)(b * T_SZ + tid) * NW32 + w] = bits;
        }
    } else if (bid < NW32 * B_SZ + NW32 * 16) {
        // --- pack W1 [512, 2312] -> W1s[h][i][256], h = o>>8
        float (*tile)[33] = (float (*)[33])lds;
        const int bb = bid - NW32 * B_SZ;
        const int i0 = (bb % NW32) * 32, o0 = (bb / NW32) * 32;
        const int tx = tid & 31, ty = tid >> 5;  // ty 0..11
#pragma unroll
        for (int r = 0; r < 3; ++r) {
            int row = ty + 12 * r;
            if (row < 32) {
                int o = o0 + row, i = i0 + tx;
                if (i < NIN) tile[row][tx] = W1[(size_t)o * NIN + i];
            }
        }
        __syncthreads();
#pragma unroll
        for (int r = 0; r < 3; ++r) {
            int row = ty + 12 * r;
            if (row < 32) {
                int i = i0 + row, o = o0 + tx;
                if (i < NIN)
                    W1s[((size_t)(o >> 8) * NROW + i) * NHALF + (o & 255)] = tile[tx][row];
            }
        }
    } else {
        // --- dummy zero row i = NIN for both halves
        if (tid < NHALF) {
            W1s[((size_t)0 * NROW + NIN) * NHALF + tid] = 0.0f;
            W1s[((size_t)1 * NROW + NIN) * NHALF + tid] = 0.0f;
        }
    }
}

// ---------------------------------------------------------------------------
// K3: sparse dense1 (R6/R10 gather form — the measured optimum: 101us,
// 26.3 TB/s L2-gather = 76% of streaming ubench). Half-split for L2
// residency; single-wave shfl prefix scan; branch-free 4-deep pipelined row
// loop via dummy zero-row padding. Batching/LDS-staging variants all lose
// (R7/R8/R9/R11/R12 post-mortems): VALU/divergence tax > traffic savings.
// R13: L2-HIT-SERVICE-RATE bound (FETCH halved, time flat) -> structural
// ceiling given the bit-exact sum order. Do not touch.
__global__ __launch_bounds__(256) void k3_dense1(const uint32_t* __restrict__ bits1,
                                                 const float* __restrict__ W1s,
                                                 float* __restrict__ z1ct) {
    __shared__ uint32_t words[128];
    __shared__ uint16_t pfx[80];
    __shared__ uint16_t idxbuf[NIN + 16];
    __shared__ float red[3][NHALF];
    __shared__ float fin[NHALF];

    const int id = blockIdx.x;
    const int h = (id >> 2) & 1;                  // XCD-affine half select
    const int bt = ((id >> 3) << 2) | (id & 3);   // b*350 + t (bijective)
    const int tid = threadIdx.x;
    const int wv = tid >> 6, lane = tid & 63;

    if (tid < 128) words[tid] = (tid < NW32) ? bits1[(size_t)bt * NW32 + tid] : 0u;
    __syncthreads();

    if (wv == 0) {
        uint32_t w0 = words[lane];
        uint32_t w1 = words[lane + 64];
        int p0 = __popc(w0), p1 = __popc(w1);
        int s0 = p0, s1 = p1;
#pragma unroll
        for (int off = 1; off < 64; off <<= 1) {
            int u0 = __shfl_up(s0, off);
            int u1 = __shfl_up(s1, off);
            if (lane >= off) { s0 += u0; s1 += u1; }
        }
        int tot0 = __shfl(s0, 63);
        pfx[lane] = (uint16_t)(s0 - p0);
        if (lane < 9) pfx[lane + 64] = (uint16_t)(tot0 + s1 - p1);
        if (lane == 8) pfx[73] = (uint16_t)(tot0 + s1);   // ntot
    }
    __syncthreads();

    const int ntot = pfx[73];
    const int npad = (ntot + 15) & ~15;
    if (tid < NW32) {
        uint32_t m = words[tid];
        int p = pfx[tid];
        while (m) {
            int j = __builtin_ctz(m);
            m &= m - 1;
            idxbuf[p++] = (uint16_t)((tid << 5) + j);
        }
    }
    if (tid >= 240) {                   // pad to multiple of 16 with zero row
        int k = tid - 240;
        if (ntot + k < npad) idxbuf[ntot + k] = (uint16_t)NIN;
    }
    __syncthreads();

    const float* Wh = W1s + (size_t)h * NROW * NHALF;
    float4 acc = make_float4(0.f, 0.f, 0.f, 0.f);
    for (int r = wv; r < npad; r += 16) {
        int i0 = idxbuf[r], i1 = idxbuf[r + 4], i2 = idxbuf[r + 8], i3 = idxbuf[r + 12];
        float4 v0 = ((const float4*)(Wh + (size_t)i0 * NHALF))[lane];
        float4 v1 = ((const float4*)(Wh + (size_t)i1 * NHALF))[lane];
        float4 v2 = ((const float4*)(Wh + (size_t)i2 * NHALF))[lane];
        float4 v3 = ((const float4*)(Wh + (size_t)i3 * NHALF))[lane];
        acc.x += v0.x; acc.y += v0.y; acc.z += v0.z; acc.w += v0.w;
        acc.x += v1.x; acc.y += v1.y; acc.z += v1.z; acc.w += v1.w;
        acc.x += v2.x; acc.y += v2.y; acc.z += v2.z; acc.w += v2.w;
        acc.x += v3.x; acc.y += v3.y; acc.z += v3.z; acc.w += v3.w;
    }
    if (wv > 0) ((float4*)red[wv - 1])[lane] = acc;
    __syncthreads();
    if (wv == 0) {
        float4 a1 = ((float4*)red[0])[lane];
        float4 a2 = ((float4*)red[1])[lane];
        float4 a3 = ((float4*)red[2])[lane];
        acc.x = ((acc.x + a1.x) + a2.x) + a3.x;
        acc.y = ((acc.y + a1.y) + a2.y) + a3.y;
        acc.z = ((acc.z + a1.z) + a2.z) + a3.z;
        acc.w = ((acc.w + a1.w) + a2.w) + a3.w;
        ((float4*)fin)[lane] = acc;
    }
    __syncthreads();
    const int och = (h << 8) + tid;
    const int oc = och >> 6, l6 = och & 63;
    const int b = bt / T_SZ, t = bt - b * T_SZ;
    z1ct[((size_t)(b * NW64 + oc) * T_SZ + t) * 64 + l6] = fin[tid];
}

// ---------------------------------------------------------------------------
// K4: layer-1 scan, de-fused (R17), BRANCH-FREE (R18). R17 post-mortem:
// k4 ran at ~880 cy/step — the ternary refills `(cond)?load:0` compile to
// branches around the loads (OOB-guard), fragmenting the loop into per-step
// basic blocks -> conservative waitcnt -> each step pays full latency.
// (Same mechanism retro-explains R1-k45's 55us and R16's seed regression.)
// Fix: unconditional loads from CLAMPED addresses + cndmask select to 0
// (single basic block, 28 loads in flight), and the lane-0 ballot store
// hoisted out of the per-step path (14 ballots flushed per outer iter).
// Ring depth & math order unchanged vs R17 -> ballots bit-identical.
__global__ __launch_bounds__(64) void k4_scan1(const float* __restrict__ z1ct,
                                               uint64_t* __restrict__ ballots) {
    const int lane = threadIdx.x;
    const int bg = blockIdx.x;                  // b*8 + g
    const float* base = z1ct + (size_t)bg * T_SZ * 64 + lane;
    const int b = bg >> 3, g = bg & 7;
    uint64_t* bout = ballots + (size_t)b * T_SZ * NW64 + g;

    double A = 0.0, Bs = 0.0, A2 = 0.0, Bs2 = 0.0;
    float ra = 0.0f, rb = 0.0f;
    const double TAIL = D100_D * CS_D;
    float xb[SNPF], xdb[SNPF];
#pragma unroll
    for (int i = 0; i < SNPF; ++i) {
        xb[i] = base[(size_t)i * 64];           // i < 350: always valid
        xdb[i] = 0.0f;                          // i-100 < 0
    }
    for (int tb = 0; tb < T_SZ; tb += SNPF) {
        uint64_t mb[SNPF];
#pragma unroll
        for (int i = 0; i < SNPF; ++i) {
            const int t = tb + i;
            float x = xb[i], xd = xdb[i];
            const int tn = t + SNPF;
            // branch-free refills: clamped unconditional load + select
            const int tcl = (tn < T_SZ) ? tn : (T_SZ - 1);
            float vb = base[(size_t)tcl * 64];
            xb[i] = (tn < T_SZ) ? vb : 0.0f;
            const int td = tn - 100;
            const int tdc = (td >= 0) ? td : 0;
            float vd = base[(size_t)tdc * 64];
            xdb[i] = (td >= 0) ? vd : 0.0f;
            Bs = DS_D * Bs + DS_D * A;
            A = DS_D * A + (double)x;
            Bs2 = DS_D * Bs2 + DS_D * A2;
            A2 = DS_D * A2 + (double)xd;
            double y = CS_D * Bs - TAIL * (Bs2 + 100.0 * A2);
            float u = (float)y + CREF_F * rb;
            float s = (u >= 10.0f) ? 1.0f : 0.0f;
            float ran = DREF_F * ra + s;
            float rbn = DREF_F * rb + DREF_F * ra;
            ra = ran; rb = rbn;
            mb[i] = __ballot(s != 0.0f);
        }
        if (lane == 0) {
#pragma unroll
            for (int i = 0; i < SNPF; ++i)
                bout[(size_t)(tb + i) * NW64] = mb[i];
        }
    }
}

// ---------------------------------------------------------------------------
// K5: dense2 from global ballots. Same (b, 50-t-chunk) grid, same thread
// mapping, same w2-ascending/ctz-ascending accumulation order as the old
// fused dense2 -> z2ct bytes identical.
__global__ __launch_bounds__(512) void k5_dense2(const uint64_t* __restrict__ ballots,
                                                 const float* __restrict__ W2,
                                                 float* __restrict__ z2ct) {
    __shared__ float W2s[NHID * NOUT];      // [c][o], 20 KB
    __shared__ uint64_t sw[CLEN][NW64];
    const int tid = threadIdx.x;
    const int b = blockIdx.x / NCHUNK;
    const int ck = blockIdx.x % NCHUNK;
    const int tstart = ck * CLEN;

    for (int k = tid; k < NHID * NOUT; k += 512) {
        int c = k / NOUT, o = k - c * NOUT;
        W2s[k] = W2[(size_t)o * NHID + c];
    }
    if (tid < CLEN * NW64) {                // 400 of 512
        const int tr = tid >> 3, g = tid & 7;
        sw[tr][g] = ballots[((size_t)(b * T_SZ + tstart + tr)) * NW64 + g];
    }
    __syncthreads();

    if (tid < CLEN * NOUT) {                // 500 of 512
        const int tr = tid / NOUT;
        const int o = tid - tr * NOUT;
        const int t = tstart + tr;
        float acc = 0.f;
#pragma unroll
        for (int w2 = 0; w2 < NW64; ++w2) {
            uint64_t m = sw[tr][w2];
            while (m) {
                int j = __builtin_ctzll(m);
                m &= m - 1;
                acc += W2s[((w2 << 6) + j) * NOUT + o];
            }
        }
        const int bo = b * NOUT + o;
        z2ct[((size_t)(bo >> 6) * T_SZ + t) * 64 + (bo & 63)] = acc;
    }
}

// ---------------------------------------------------------------------------
// K6: layer-2 psp+refractory scan, DE-CHUNKED (R18): 5 blocks x 64, full
// T=350 from t=0 — the exact truncated-FIR reference recurrence, zero
// warm-up approximation. Same branch-free clamped-load pattern as k4.
__global__ __launch_bounds__(64) void k6_fir_scan2(const float* __restrict__ z2ct,
                                                   float* __restrict__ out) {
    const int lane = threadIdx.x;
    const int g = blockIdx.x;               // bo group 0..4
    const float* base = z2ct + (size_t)g * T_SZ * 64 + lane;
    float* op = out + (size_t)((g << 6) + lane) * T_SZ;
    double A = 0.0, Bs = 0.0, A2 = 0.0, Bs2 = 0.0;
    float ra = 0.0f, rb = 0.0f;
    const double TAIL = D100_D * CS_D;
    float xb[SNPF], xdb[SNPF];
#pragma unroll
    for (int i = 0; i < SNPF; ++i) {
        xb[i] = base[(size_t)i * 64];
        xdb[i] = 0.0f;
    }
    for (int tb = 0; tb < T_SZ; tb += SNPF) {
#pragma unroll
        for (int i = 0; i < SNPF; ++i) {
            const int t = tb + i;
            float x = xb[i], xd = xdb[i];
            const int tn = t + SNPF;
            const int tcl = (tn < T_SZ) ? tn : (T_SZ - 1);
            float vb = base[(size_t)tcl * 64];
            xb[i] = (tn < T_SZ) ? vb : 0.0f;
            const int td = tn - 100;
            const int tdc = (td >= 0) ? td : 0;
            float vd = base[(size_t)tdc * 64];
            xdb[i] = (td >= 0) ? vd : 0.0f;
            Bs = DS_D * Bs + DS_D * A;
            A = DS_D * A + (double)x;
            Bs2 = DS_D * Bs2 + DS_D * A2;
            A2 = DS_D * A2 + (double)xd;
            double y = CS_D * Bs - TAIL * (Bs2 + 100.0 * A2);
            float u = (float)y + CREF_F * rb;
            float s = (u >= 10.0f) ? 1.0f : 0.0f;
            float ran = DREF_F * ra + s;
            float rbn = DREF_F * rb + DREF_F * ra;
            ra = ran; rb = rbn;
            op[t] = s;
        }
    }
}

// ---------------------------------------------------------------------------
extern "C" void kernel_launch(void* const* d_in, const int* in_sizes, int n_in,
                              void* d_out, int out_size, void* d_ws, size_t ws_size,
                              hipStream_t stream) {
    const float* spikeInput = (const float*)d_in[0];  // [32, 2312, 350]
    const float* W1 = (const float*)d_in[1];          // [512, 2312]
    const float* W2 = (const float*)d_in[2];          // [10, 512]
    float* out = (float*)d_out;                       // [32, 10, 350]

    char* ws = (char*)d_ws;
    float* W1s = (float*)(ws + 0);                        //  4,737,024 B (2313 rows x 2 halves)
    uint32_t* bits1 = (uint32_t*)(ws + 4737024);          //  3,270,400 B
    float* z1ct = (float*)(ws + 8007424);                 // 22,937,600 B
    // Aliases into bits1's region (bits1 dead after k3):
    //   z2ct    @ +4,737,024 (448,000 B), written by k5, read by k6
    //   ballots @ +5,185,024 (716,800 B), written by k4, read by k5
    float* z2ct = (float*)(ws + 4737024);
    uint64_t* ballots = (uint64_t*)(ws + 5185024);
    // total high-water: 30,945,024 B

    k12<<<NW32 * B_SZ + NW32 * 16 + 1, 384, 0, stream>>>(spikeInput, W1, bits1, W1s);
    k3_dense1<<<B_SZ * T_SZ * 2, 256, 0, stream>>>(bits1, W1s, z1ct);
    k4_scan1<<<B_SZ * NW64, 64, 0, stream>>>(z1ct, ballots);
    k5_dense2<<<B_SZ * NCHUNK, 512, 0, stream>>>(ballots, W2, z2ct);
    k6_fir_scan2<<<5, 64, 0, stream>>>(z2ct, out);
}

// Round 7
// 295.869 us; speedup vs baseline: 1.3810x; 1.1012x over previous
//
#include <hip/hip_runtime.h>
#include <stdint.h>

// Problem constants
#define B_SZ   32
#define NIN    2312
#define NHID   512
#define NOUT   10
#define T_SZ   350
#define NW32   73                 // ceil(2312/32) bitmask words per input column
#define NW64   8                  // 512/64 ballot words per hidden column
#define NHALF  256                // output half-width for L2-resident W1
#define NROW   2313               // NIN + 1 dummy zero row (branch-free padding)

// psp (SRM) kernel eps[n] = CS * n * DS^n, DS = exp(-0.1), CS = e/10
#define DS_D   0.9048374180359595
#define CS_D   0.2718281828459045
#define D100_D 4.5399929762484854e-05   // exp(-10) = DS^100
// refractory recurrence in fp32, exactly like the reference scan
#define DREF_F 0.36787944117144233f     // exp(-1)
#define CREF_F -54.36563656918091f      // -2*10*e

// scan chunking (k45/k6): 7 chunks of 50; psp-IIR warm-started <=100 steps
// (EXACT: FIR truncated at 100 taps); refractory burn-in error decays e^-n.
// R19: R1 topology restored (proven 315.8us). Single change vs R1: the scan
// inner loops are BRANCH-FREE — refills load from clamped addresses with a
// cndmask select to 0 (no branch-around-load basic-block fragmentation),
// and stores are register-collected and flushed once per NPF-step group
// under a UNIFORM branch (tstart % NPF == 0 -> whole groups emit or skip).
// Arithmetic order identical to R1 -> output bit-identical.
#define NCHUNK 7
#define CLEN   50
#define NPF    10                 // ring depth; 50/100/150 all %10==0

// ---------------------------------------------------------------------------
// K12: fused bitpack (blocks 0..2335) + W1 half-split pack (2336..3503) +
//      dummy-zero-row fill (block 3504). Bitpack float4 streaming.
__global__ __launch_bounds__(384) void k12(const float* __restrict__ x,
                                           const float* __restrict__ W1,
                                           uint32_t* __restrict__ bits1,
                                           float* __restrict__ W1s) {
    __shared__ float lds[32 * T_SZ];   // 44.8 KB
    const int bid = blockIdx.x;
    const int tid = threadIdx.x;
    if (bid < NW32 * B_SZ) {
        // --- bitpack: block = (b, w); contiguous rowsx350 tile -> LDS -> pack
        const int w = bid % NW32;
        const int b = bid / NW32;
        const int rows = (NIN - (w << 5) < 32) ? (NIN - (w << 5)) : 32;  // 32 or 8
        const float* base = x + ((size_t)(b * NIN + (w << 5))) * T_SZ;
        const int nf4 = (rows * T_SZ) >> 2;     // rows even -> divisible by 4
        for (int f = tid; f < nf4; f += 384)
            ((float4*)lds)[f] = ((const float4*)base)[f];
        __syncthreads();
        if (tid < T_SZ) {
            uint32_t bits = 0;
            for (int j = 0; j < rows; ++j)
                bits |= (lds[j * T_SZ + tid] > 0.5f) ? (1u << j) : 0u;
            bits1[(size_t)(b * T_SZ + tid) * NW32 + w] = bits;
        }
    } else if (bid < NW32 * B_SZ + NW32 * 16) {
        // --- pack W1 [512, 2312] -> W1s[h][i][256], h = o>>8
        float (*tile)[33] = (float (*)[33])lds;
        const int bb = bid - NW32 * B_SZ;
        const int i0 = (bb % NW32) * 32, o0 = (bb / NW32) * 32;
        const int tx = tid & 31, ty = tid >> 5;  // ty 0..11
#pragma unroll
        for (int r = 0; r < 3; ++r) {
            int row = ty + 12 * r;
            if (row < 32) {
                int o = o0 + row, i = i0 + tx;
                if (i < NIN) tile[row][tx] = W1[(size_t)o * NIN + i];
            }
        }
        __syncthreads();
#pragma unroll
        for (int r = 0; r < 3; ++r) {
            int row = ty + 12 * r;
            if (row < 32) {
                int i = i0 + row, o = o0 + tx;
                if (i < NIN)
                    W1s[((size_t)(o >> 8) * NROW + i) * NHALF + (o & 255)] = tile[tx][row];
            }
        }
    } else {
        // --- dummy zero row i = NIN for both halves
        if (tid < NHALF) {
            W1s[((size_t)0 * NROW + NIN) * NHALF + tid] = 0.0f;
            W1s[((size_t)1 * NROW + NIN) * NHALF + tid] = 0.0f;
        }
    }
}

// ---------------------------------------------------------------------------
// K3: sparse dense1 (R6/R10 gather form — the measured optimum: 101us,
// 26.3 TB/s L2-gather = 76% of streaming ubench). Half-split for L2
// residency; single-wave shfl prefix scan; branch-free 4-deep pipelined row
// loop via dummy zero-row padding. R13: L2-HIT-SERVICE-RATE bound ->
// structural ceiling given the bit-exact sum order. Do not touch.
__global__ __launch_bounds__(256) void k3_dense1(const uint32_t* __restrict__ bits1,
                                                 const float* __restrict__ W1s,
                                                 float* __restrict__ z1ct) {
    __shared__ uint32_t words[128];
    __shared__ uint16_t pfx[80];
    __shared__ uint16_t idxbuf[NIN + 16];
    __shared__ float red[3][NHALF];
    __shared__ float fin[NHALF];

    const int id = blockIdx.x;
    const int h = (id >> 2) & 1;                  // XCD-affine half select
    const int bt = ((id >> 3) << 2) | (id & 3);   // b*350 + t (bijective)
    const int tid = threadIdx.x;
    const int wv = tid >> 6, lane = tid & 63;

    if (tid < 128) words[tid] = (tid < NW32) ? bits1[(size_t)bt * NW32 + tid] : 0u;
    __syncthreads();

    if (wv == 0) {
        uint32_t w0 = words[lane];
        uint32_t w1 = words[lane + 64];
        int p0 = __popc(w0), p1 = __popc(w1);
        int s0 = p0, s1 = p1;
#pragma unroll
        for (int off = 1; off < 64; off <<= 1) {
            int u0 = __shfl_up(s0, off);
            int u1 = __shfl_up(s1, off);
            if (lane >= off) { s0 += u0; s1 += u1; }
        }
        int tot0 = __shfl(s0, 63);
        pfx[lane] = (uint16_t)(s0 - p0);
        if (lane < 9) pfx[lane + 64] = (uint16_t)(tot0 + s1 - p1);
        if (lane == 8) pfx[73] = (uint16_t)(tot0 + s1);   // ntot
    }
    __syncthreads();

    const int ntot = pfx[73];
    const int npad = (ntot + 15) & ~15;
    if (tid < NW32) {
        uint32_t m = words[tid];
        int p = pfx[tid];
        while (m) {
            int j = __builtin_ctz(m);
            m &= m - 1;
            idxbuf[p++] = (uint16_t)((tid << 5) + j);
        }
    }
    if (tid >= 240) {                   // pad to multiple of 16 with zero row
        int k = tid - 240;
        if (ntot + k < npad) idxbuf[ntot + k] = (uint16_t)NIN;
    }
    __syncthreads();

    const float* Wh = W1s + (size_t)h * NROW * NHALF;
    float4 acc = make_float4(0.f, 0.f, 0.f, 0.f);
    for (int r = wv; r < npad; r += 16) {
        int i0 = idxbuf[r], i1 = idxbuf[r + 4], i2 = idxbuf[r + 8], i3 = idxbuf[r + 12];
        float4 v0 = ((const float4*)(Wh + (size_t)i0 * NHALF))[lane];
        float4 v1 = ((const float4*)(Wh + (size_t)i1 * NHALF))[lane];
        float4 v2 = ((const float4*)(Wh + (size_t)i2 * NHALF))[lane];
        float4 v3 = ((const float4*)(Wh + (size_t)i3 * NHALF))[lane];
        acc.x += v0.x; acc.y += v0.y; acc.z += v0.z; acc.w += v0.w;
        acc.x += v1.x; acc.y += v1.y; acc.z += v1.z; acc.w += v1.w;
        acc.x += v2.x; acc.y += v2.y; acc.z += v2.z; acc.w += v2.w;
        acc.x += v3.x; acc.y += v3.y; acc.z += v3.z; acc.w += v3.w;
    }
    if (wv > 0) ((float4*)red[wv - 1])[lane] = acc;
    __syncthreads();
    if (wv == 0) {
        float4 a1 = ((float4*)red[0])[lane];
        float4 a2 = ((float4*)red[1])[lane];
        float4 a3 = ((float4*)red[2])[lane];
        acc.x = ((acc.x + a1.x) + a2.x) + a3.x;
        acc.y = ((acc.y + a1.y) + a2.y) + a3.y;
        acc.z = ((acc.z + a1.z) + a2.z) + a3.z;
        acc.w = ((acc.w + a1.w) + a2.w) + a3.w;
        ((float4*)fin)[lane] = acc;
    }
    __syncthreads();
    const int och = (h << 8) + tid;
    const int oc = och >> 6, l6 = och & 63;
    const int b = bt / T_SZ, t = bt - b * T_SZ;
    z1ct[((size_t)(b * NW64 + oc) * T_SZ + t) * 64 + l6] = fin[tid];
}

// ---------------------------------------------------------------------------
// K45: fused layer-1 scan + dense2 (R1 topology). R19: branch-free refills
// (clamped load + select) and per-tb register-collected ballot flush under a
// uniform branch. Math order identical to R1 -> bit-identical output.
__global__ __launch_bounds__(512) void k45(const float* __restrict__ z1ct,
                                           const float* __restrict__ W2,
                                           float* __restrict__ z2ct) {
    __shared__ float W2s[NHID * NOUT];      // [c][o], 20 KB
    __shared__ uint64_t sw[CLEN][NW64];     // s1 ballot words for my 50 t's
    const int tid = threadIdx.x;
    const int wv = tid >> 6, lane = tid & 63;
    const int b = blockIdx.x / NCHUNK;
    const int ck = blockIdx.x % NCHUNK;
    const int tstart = ck * CLEN;
    const int tend = tstart + CLEN;
    const int t0 = (tstart >= 100) ? tstart - 100 : 0;

    for (int k = tid; k < NHID * NOUT; k += 512) {
        int c = k / NOUT, o = k - c * NOUT;
        W2s[k] = W2[(size_t)o * NHID + c];
    }

    // ---- layer-1 chunked scan (identical math to R1)
    const float* base = z1ct + (size_t)(b * NW64 + wv) * T_SZ * 64 + lane;
    double A = 0.0, Bs = 0.0, A2 = 0.0, Bs2 = 0.0;
    float ra = 0.0f, rb = 0.0f;
    const double TAIL = D100_D * CS_D;
    float xb[NPF], xdb[NPF];
#pragma unroll
    for (int i = 0; i < NPF; ++i) {
        const int t = t0 + i;                       // < 350: always valid
        xb[i] = base[(size_t)t * 64];
        const int td = t - 100;
        const int tdc = (td >= 0) ? td : 0;
        float vd = base[(size_t)tdc * 64];          // unconditional
        xdb[i] = (td >= 0) ? vd : 0.0f;             // select, no branch
    }
    for (int tb = t0; tb < tend; tb += NPF) {
        uint64_t mb[NPF];
#pragma unroll
        for (int i = 0; i < NPF; ++i) {
            const int t = tb + i;
            float x = xb[i], xd = xdb[i];
            const int tn = t + NPF;
            const int tcl = (tn < T_SZ) ? tn : (T_SZ - 1);
            float vb = base[(size_t)tcl * 64];      // unconditional (clamped)
            xb[i] = (tn < T_SZ) ? vb : 0.0f;
            const int td = tn - 100;
            const int tdc = (td >= 0) ? td : 0;
            float vd = base[(size_t)tdc * 64];      // unconditional (clamped)
            xdb[i] = (td >= 0) ? vd : 0.0f;
            Bs = DS_D * Bs + DS_D * A;
            A = DS_D * A + (double)x;
            Bs2 = DS_D * Bs2 + DS_D * A2;
            A2 = DS_D * A2 + (double)xd;
            double y = CS_D * Bs - TAIL * (Bs2 + 100.0 * A2);
            float u = (float)y + CREF_F * rb;
            float s = (u >= 10.0f) ? 1.0f : 0.0f;
            float ran = DREF_F * ra + s;
            float rbn = DREF_F * rb + DREF_F * ra;
            ra = ran; rb = rbn;
            mb[i] = __ballot(s != 0.0f);
        }
        // uniform per-tb flush: tstart % NPF == 0 -> whole group emits or not
        if (tb >= tstart && lane == 0) {
#pragma unroll
            for (int i = 0; i < NPF; ++i)
                sw[tb - tstart + i][wv] = mb[i];
        }
    }
    __syncthreads();

    // ---- dense2 for my 50 t's (same order as R1 -> bit-identical)
    if (tid < CLEN * NOUT) {                // 500 of 512
        const int tr = tid / NOUT;
        const int o = tid - tr * NOUT;
        const int t = tstart + tr;
        float acc = 0.f;
#pragma unroll
        for (int w2 = 0; w2 < NW64; ++w2) {
            uint64_t m = sw[tr][w2];
            while (m) {
                int j = __builtin_ctzll(m);
                m &= m - 1;
                acc += W2s[((w2 << 6) + j) * NOUT + o];
            }
        }
        const int bo = b * NOUT + o;
        z2ct[((size_t)(bo >> 6) * T_SZ + t) * 64 + (bo & 63)] = acc;
    }
}

// ---------------------------------------------------------------------------
// K6: fused psp-IIR + refractory scan, layer 2, chunked (R1 topology).
// R19: branch-free refills + per-tb register-collected output flush.
__global__ __launch_bounds__(64) void k6_fir_scan2(const float* __restrict__ z2ct,
                                                   float* __restrict__ out) {
    const int lane = threadIdx.x;
    const int g = blockIdx.x / NCHUNK;    // bo group 0..4
    const int ck = blockIdx.x % NCHUNK;
    const int tstart = ck * CLEN;
    const int tend = tstart + CLEN;
    const int t0 = (tstart >= 100) ? tstart - 100 : 0;
    const int bo = (g << 6) + lane;       // 0..319
    const float* base = z2ct + (size_t)g * T_SZ * 64 + lane;
    float* op = out + (size_t)bo * T_SZ;
    double A = 0.0, Bs = 0.0, A2 = 0.0, Bs2 = 0.0;
    float ra = 0.0f, rb = 0.0f;
    const double TAIL = D100_D * CS_D;
    float xb[NPF], xdb[NPF];
#pragma unroll
    for (int i = 0; i < NPF; ++i) {
        const int t = t0 + i;
        xb[i] = base[(size_t)t * 64];
        const int td = t - 100;
        const int tdc = (td >= 0) ? td : 0;
        float vd = base[(size_t)tdc * 64];
        xdb[i] = (td >= 0) ? vd : 0.0f;
    }
    for (int tb = t0; tb < tend; tb += NPF) {
        float sb[NPF];
#pragma unroll
        for (int i = 0; i < NPF; ++i) {
            const int t = tb + i;
            float x = xb[i], xd = xdb[i];
            const int tn = t + NPF;
            const int tcl = (tn < T_SZ) ? tn : (T_SZ - 1);
            float vb = base[(size_t)tcl * 64];
            xb[i] = (tn < T_SZ) ? vb : 0.0f;
            const int td = tn - 100;
            const int tdc = (td >= 0) ? td : 0;
            float vd = base[(size_t)tdc * 64];
            xdb[i] = (td >= 0) ? vd : 0.0f;
            Bs = DS_D * Bs + DS_D * A;
            A = DS_D * A + (double)x;
            Bs2 = DS_D * Bs2 + DS_D * A2;
            A2 = DS_D * A2 + (double)xd;
            double y = CS_D * Bs - TAIL * (Bs2 + 100.0 * A2);
            float u = (float)y + CREF_F * rb;
            float s = (u >= 10.0f) ? 1.0f : 0.0f;
            float ran = DREF_F * ra + s;
            float rbn = DREF_F * rb + DREF_F * ra;
            ra = ran; rb = rbn;
            sb[i] = s;
        }
        if (tb >= tstart) {                 // uniform per-tb flush
#pragma unroll
            for (int i = 0; i < NPF; ++i)
                op[tb + i] = sb[i];
        }
    }
}

// ---------------------------------------------------------------------------
extern "C" void kernel_launch(void* const* d_in, const int* in_sizes, int n_in,
                              void* d_out, int out_size, void* d_ws, size_t ws_size,
                              hipStream_t stream) {
    const float* spikeInput = (const float*)d_in[0];  // [32, 2312, 350]
    const float* W1 = (const float*)d_in[1];          // [512, 2312]
    const float* W2 = (const float*)d_in[2];          // [10, 512]
    float* out = (float*)d_out;                       // [32, 10, 350]

    char* ws = (char*)d_ws;
    float* W1s = (float*)(ws + 0);                        //  4,737,024 B (2313 rows x 2 halves)
    uint32_t* bits1 = (uint32_t*)(ws + 4737024);          //  3,270,400 B
    float* z1ct = (float*)(ws + 8007424);                 // 22,937,600 B
    // z2ct aliases bits1's region: bits1 is dead after k3, z2ct written by k45.
    float* z2ct = (float*)(ws + 4737024);                 //    448,000 B (alias)
    // total: 30,945,024 B

    k12<<<NW32 * B_SZ + NW32 * 16 + 1, 384, 0, stream>>>(spikeInput, W1, bits1, W1s);
    k3_dense1<<<B_SZ * T_SZ * 2, 256, 0, stream>>>(bits1, W1s, z1ct);
    k45<<<B_SZ * NCHUNK, 512, 0, stream>>>(z1ct, W2, z2ct);
    k6_fir_scan2<<<5 * NCHUNK, 64, 0, stream>>>(z2ct, out);
}